// Round 6
// baseline (132.791 us; speedup 1.0000x reference)
//
#include <hip/hip_runtime.h>
#include <math.h>

// SimpleMamba: s_t = A*s_{t-1} + B*x_t ; y_t = tanh(C*s_t), per-channel.
// L=8192, D=2048, f32.
//
// R6 (fused-v2): persistent-grid fused kernel, but x is NOT held in registers
// across the barrier (R5's xr[32] was demoted to scratch -> 64 MiB spill round
// trip -> 101 us). Phase C re-reads x from global instead: phase A just streamed
// x through the caches and 64 MiB << 256 MiB L3, so the re-read is L3-served.
// VGPR stays ~64-96 -> no spill, 512 blocks trivially co-resident.
// CL=32 pinned by f32 overflow (A^32 finite for max|A|~3.9; A^64 would overflow).
// Scan stays a flat serial chain (tree compose is inf-inf NaN-unsafe for |A|>1).

#define LL 8192
#define DD 2048
#define CL 32
#define NC (LL / CL)          // 256 chunks
#define G4 (DD / 4)           // 512 float4 channel-groups
#define NBLK (NC * G4 / 256)  // 512 blocks
#define NSCAN (DD / 256)      // 8 scan blocks (2048 scan threads, 1/channel)

__device__ __forceinline__ float fast_tanh(float z)
{
    // tanh(z) = 1 - 2/(exp2(2z*log2e)+1); exact saturation at +-inf, ~1e-7 err.
    float e = __builtin_amdgcn_exp2f(z * 2.885390081777927f);
    return 1.0f - 2.0f * __builtin_amdgcn_rcpf(e + 1.0f);
}

__global__ __launch_bounds__(256) void mamba_fused(
    const float4* __restrict__ x4, const float4* __restrict__ A4,
    const float4* __restrict__ B4, const float4* __restrict__ C4,
    float4* __restrict__ loc4, float4* __restrict__ car4,
    unsigned* __restrict__ cnt, float4* __restrict__ y4)
{
    const int lin   = blockIdx.x * 256 + threadIdx.x;
    const int chunk = lin >> 9;          // / G4
    const int grp   = lin & (G4 - 1);

    const float4 a = A4[grp];
    const float4 b = B4[grp];

    const size_t base = (size_t)chunk * CL * G4 + grp;

    // ---- phase A: chunk-local end state from s=0 (streaming read of x) ----
    float sx = 0.f, sy = 0.f, sz = 0.f, sw = 0.f;
    #pragma unroll
    for (int t0 = 0; t0 < CL; t0 += 8) {
        float4 v[8];
        #pragma unroll
        for (int k = 0; k < 8; ++k)
            v[k] = x4[base + (size_t)(t0 + k) * G4];   // 8 dwordx4 in flight
        #pragma unroll
        for (int k = 0; k < 8; ++k) {
            sx = fmaf(a.x, sx, b.x * v[k].x);
            sy = fmaf(a.y, sy, b.y * v[k].y);
            sz = fmaf(a.z, sz, b.z * v[k].z);
            sw = fmaf(a.w, sw, b.w * v[k].w);
        }
    }
    loc4[(size_t)chunk * G4 + grp] = make_float4(sx, sy, sz, sw);

    // ---- barrier 1 arrive (wait-free; only scanners poll) ----
    __syncthreads();                       // all lanes' loc stores issued
    if (threadIdx.x == 0) {
        __threadfence();                   // release loc to device scope
        __hip_atomic_fetch_add(&cnt[0], 1u, __ATOMIC_RELAXED, __HIP_MEMORY_SCOPE_AGENT);
    }

    // ---- phase B: 8 scan blocks do the serial carry chain ----
    if (blockIdx.x < NSCAN) {
        if (threadIdx.x == 0) {
            while (__hip_atomic_load(&cnt[0], __ATOMIC_RELAXED, __HIP_MEMORY_SCOPE_AGENT) < NBLK)
                __builtin_amdgcn_s_sleep(2);
            __threadfence();               // acquire: fresh loc
        }
        __syncthreads();

        const int ch = blockIdx.x * 256 + threadIdx.x;   // 0..DD-1
        const float* loc = (const float*)loc4;
        float*       car = (float*)car4;

        float p = ((const float*)A4)[ch];  // A^32 via 5 squarings (finite)
        #pragma unroll
        for (int i = 0; i < 5; ++i) p *= p;

        float c = 0.f;
        for (int c0 = 0; c0 < NC; c0 += 32) {
            float lv[32];
            #pragma unroll
            for (int k = 0; k < 32; ++k)
                lv[k] = loc[(size_t)(c0 + k) * DD + ch];    // 32 loads in flight
            #pragma unroll
            for (int k = 0; k < 32; ++k) {
                car[(size_t)(c0 + k) * DD + ch] = c;
                c = fmaf(p, c, lv[k]);     // lv finite -> no inf-inf NaN
            }
        }

        __syncthreads();                   // all car stores issued
        if (threadIdx.x == 0) {
            __threadfence();               // release car
            __hip_atomic_fetch_add(&cnt[1], 1u, __ATOMIC_RELAXED, __HIP_MEMORY_SCOPE_AGENT);
        }
    }

    // ---- barrier 2 wait (everyone; only scan blocks increment cnt[1]) ----
    if (threadIdx.x == 0) {
        while (__hip_atomic_load(&cnt[1], __ATOMIC_RELAXED, __HIP_MEMORY_SCOPE_AGENT) < NSCAN)
            __builtin_amdgcn_s_sleep(2);
        __threadfence();                   // acquire: fresh car
    }
    __syncthreads();

    // ---- phase C: rerun recurrence from carry; x re-read is L3-served ----
    const float4 cc = C4[grp];
    float4 s0 = car4[(size_t)chunk * G4 + grp];
    sx = s0.x; sy = s0.y; sz = s0.z; sw = s0.w;

    #pragma unroll
    for (int t0 = 0; t0 < CL; t0 += 8) {
        float4 v[8];
        #pragma unroll
        for (int k = 0; k < 8; ++k)
            v[k] = x4[base + (size_t)(t0 + k) * G4];   // 8 dwordx4 in flight (L3 hit)
        #pragma unroll
        for (int k = 0; k < 8; ++k) {
            sx = fmaf(a.x, sx, b.x * v[k].x);
            sy = fmaf(a.y, sy, b.y * v[k].y);
            sz = fmaf(a.z, sz, b.z * v[k].z);
            sw = fmaf(a.w, sw, b.w * v[k].w);
            y4[base + (size_t)(t0 + k) * G4] =
                make_float4(fast_tanh(cc.x * sx), fast_tanh(cc.y * sy),
                            fast_tanh(cc.z * sz), fast_tanh(cc.w * sw));
        }
    }
}

extern "C" void kernel_launch(void* const* d_in, const int* in_sizes, int n_in,
                              void* d_out, int out_size, void* d_ws, size_t ws_size,
                              hipStream_t stream)
{
    const float4* x4 = (const float4*)d_in[0];   // [L, D] f32
    const float4* A4 = (const float4*)d_in[1];   // [D]
    const float4* B4 = (const float4*)d_in[2];   // [D]
    const float4* C4 = (const float4*)d_in[3];   // [D]
    float4* y4 = (float4*)d_out;                 // [L, D] f32

    float4* loc4 = (float4*)d_ws;                       // 2 MiB
    float4* car4 = loc4 + (size_t)NC * G4;              // 2 MiB
    unsigned* cnt = (unsigned*)((char*)d_ws + (size_t)NC * DD * 4 * 2);

    (void)hipMemsetAsync(cnt, 0, 16, stream);           // counters start at 0 each call
    mamba_fused<<<NBLK, 256, 0, stream>>>(x4, A4, B4, C4, loc4, car4, cnt, y4);
}

// Round 7
// 48.574 us; speedup vs baseline: 2.7338x; 2.7338x over previous
//
#include <hip/hip_runtime.h>
#include <math.h>

// SimpleMamba: s_t = A*s_{t-1} + B*x_t ; y_t = tanh(C*s_t), per-channel.
// L=8192, D=2048, f32.
//
// R7: revert to the 3-kernel chunked scan (R3, measured 48.4 us) — two rounds of
// evidence show a device-wide spin barrier costs 60-90 us on this chip, far more
// than the ~5 us of stream-ordered launch gaps it replaces. Changes vs R3:
//   p3 uses nontemporal y stores (y never re-read; avoid L2 write-allocate which
//   was throttling p3 to ~4.3 TB/s and evicting the x it re-reads), and p1 uses
//   16-deep explicit load batching.
// CL=32 pinned by f32 overflow (A^32 finite for max|A|~3.9; CL=64 would make
// chunk-local sums overflow -> +-inf locs -> inf-inf = NaN in the carry chain).
// Carry chain stays flat-serial (tree compose is inf-inf NaN-unsafe for |A|>1).

#define LL 8192
#define DD 2048
#define CL 32
#define NC (LL / CL)   // 256 chunks
#define G4 (DD / 4)    // 512 float4 channel-groups per row

typedef float f32x4 __attribute__((ext_vector_type(4)));  // for nontemporal store

__device__ __forceinline__ float fast_tanh(float z)
{
    // tanh(z) = 1 - 2/(exp2(2z*log2e)+1); exact saturation at +-inf, ~1e-7 err.
    float e = __builtin_amdgcn_exp2f(z * 2.885390081777927f);
    return 1.0f - 2.0f * __builtin_amdgcn_rcpf(e + 1.0f);
}

// ---------------- Phase 1: per-chunk local end-state (from s=0) ----------------
__global__ __launch_bounds__(256) void mamba_p1(
    const float4* __restrict__ x4, const float4* __restrict__ A4,
    const float4* __restrict__ B4, float4* __restrict__ loc4)
{
    int lin   = blockIdx.x * 256 + threadIdx.x;   // NC * G4 threads
    int chunk = lin >> 9;                         // / G4
    int grp   = lin & (G4 - 1);

    float4 a = A4[grp];
    float4 b = B4[grp];
    float sx = 0.f, sy = 0.f, sz = 0.f, sw = 0.f;

    const float4* xp = x4 + (size_t)chunk * CL * G4 + grp;
    #pragma unroll
    for (int t0 = 0; t0 < CL; t0 += 16) {
        float4 v[16];
        #pragma unroll
        for (int k = 0; k < 16; ++k)
            v[k] = xp[(size_t)(t0 + k) * G4];     // 16 dwordx4 in flight
        #pragma unroll
        for (int k = 0; k < 16; ++k) {
            sx = fmaf(a.x, sx, b.x * v[k].x);
            sy = fmaf(a.y, sy, b.y * v[k].y);
            sz = fmaf(a.z, sz, b.z * v[k].z);
            sw = fmaf(a.w, sw, b.w * v[k].w);
        }
    }
    loc4[(size_t)chunk * G4 + grp] = make_float4(sx, sy, sz, sw);
}

// ---------------- Phase 2: serial scan over chunks, one thread per CHANNEL ----------------
// carry[c] = state entering chunk c; carry[c+1] = A^CL * carry[c] + loc[c].
// 2048 threads over 32 blocks. 64-deep load batches -> 4 latency stalls.
__global__ __launch_bounds__(64) void mamba_p2(
    const float* __restrict__ A, const float* __restrict__ loc,
    float* __restrict__ car)
{
    int ch = blockIdx.x * 64 + threadIdx.x;       // 0..DD-1
    float p = A[ch];
    #pragma unroll
    for (int i = 0; i < 5; ++i) p *= p;           // A^32, finite (3.9^32 ~ 8e18)

    float c = 0.f;
    for (int c0 = 0; c0 < NC; c0 += 64) {
        float lv[64];
        #pragma unroll
        for (int k = 0; k < 64; ++k)
            lv[k] = loc[(size_t)(c0 + k) * DD + ch];   // 64 loads in flight
        #pragma unroll
        for (int k = 0; k < 64; ++k) {
            car[(size_t)(c0 + k) * DD + ch] = c;
            c = fmaf(p, c, lv[k]);                     // lv finite -> no inf-inf
        }
    }
}

// ---------------- Phase 3: recompute recurrence from carry, emit tanh(C*s) ----------------
__global__ __launch_bounds__(256) void mamba_p3(
    const float4* __restrict__ x4, const float4* __restrict__ A4,
    const float4* __restrict__ B4, const float4* __restrict__ C4,
    const float4* __restrict__ car4, float4* __restrict__ y4)
{
    int lin   = blockIdx.x * 256 + threadIdx.x;
    int chunk = lin >> 9;
    int grp   = lin & (G4 - 1);

    float4 a = A4[grp];
    float4 b = B4[grp];
    float4 c = C4[grp];
    float4 s0 = car4[(size_t)chunk * G4 + grp];
    float sx = s0.x, sy = s0.y, sz = s0.z, sw = s0.w;

    const float4* xp = x4 + (size_t)chunk * CL * G4 + grp;
    float4*       yp = y4 + (size_t)chunk * CL * G4 + grp;

    #pragma unroll
    for (int t0 = 0; t0 < CL; t0 += 8) {
        float4 v[8];
        #pragma unroll
        for (int k = 0; k < 8; ++k)
            v[k] = xp[(size_t)(t0 + k) * G4];     // 8 dwordx4 in flight (L3-warm)
        #pragma unroll
        for (int k = 0; k < 8; ++k) {
            sx = fmaf(a.x, sx, b.x * v[k].x);
            sy = fmaf(a.y, sy, b.y * v[k].y);
            sz = fmaf(a.z, sz, b.z * v[k].z);
            sw = fmaf(a.w, sw, b.w * v[k].w);
            f32x4 o;
            o.x = fast_tanh(c.x * sx);
            o.y = fast_tanh(c.y * sy);
            o.z = fast_tanh(c.z * sz);
            o.w = fast_tanh(c.w * sw);
            // y is never re-read: bypass L2 write-allocate
            __builtin_nontemporal_store(o, (f32x4*)&yp[(size_t)(t0 + k) * G4]);
        }
    }
}

extern "C" void kernel_launch(void* const* d_in, const int* in_sizes, int n_in,
                              void* d_out, int out_size, void* d_ws, size_t ws_size,
                              hipStream_t stream)
{
    const float4* x4 = (const float4*)d_in[0];   // [L, D] f32
    const float*  Af = (const float*)d_in[1];
    const float4* A4 = (const float4*)d_in[1];   // [D]
    const float4* B4 = (const float4*)d_in[2];   // [D]
    const float4* C4 = (const float4*)d_in[3];   // [D]
    float4* y4 = (float4*)d_out;                 // [L, D] f32

    // workspace: loc (NC*D f32 = 2 MiB) + carry (2 MiB)
    float*  locf = (float*)d_ws;
    float4* loc4 = (float4*)d_ws;
    float*  carf = locf + (size_t)NC * DD;
    float4* car4 = (float4*)carf;

    const int nthreads = NC * G4;                // 131072
    mamba_p1<<<nthreads / 256, 256, 0, stream>>>(x4, A4, B4, loc4);
    mamba_p2<<<DD / 64, 64, 0, stream>>>(Af, locf, carf);
    mamba_p3<<<nthreads / 256, 256, 0, stream>>>(x4, A4, B4, C4, car4, y4);
}